// Round 8
// baseline (24.074 us; speedup 1.0000x reference)
//
#include <hip/hip_runtime.h>
#include <math.h>

#define N_PTS  1000000
#define M_COMP 64

typedef float v2f __attribute__((ext_vector_type(2)));

__device__ __forceinline__ float exp2n(float x) { return __builtin_amdgcn_exp2f(x); }
__device__ __forceinline__ float log2n(float x) { return __builtin_amdgcn_logf(x); }

// ---------------------------------------------------------------------------
// Kernel 1 (1 block, 64 threads): per-component coefficients of
//   s_ij = -g00*x0^2 - 2g01*x0*x1 - g11*x1^2 + 2Gmu0*x0 + 2Gmu1*x1
//          + (wlog - mu^T G mu),   all pre-scaled by log2(e),
// written SoA cf[k][64] to d_ws. 1.5 KB -> L1/L2-hot for the main kernel.
// ---------------------------------------------------------------------------
__global__ __launch_bounds__(64) void gm_coef(
    const float* __restrict__ mu,   // (64,2)
    const float* __restrict__ A,    // (64,2,2)
    const float* __restrict__ w,    // (64,1)
    float* __restrict__ cf)         // (6,64) in d_ws
{
    const int j = threadIdx.x;
    const float L2E = 1.4426950408889634f;
    const float LN2 = 0.6931471805599453f;

    const float a00 = A[j*4+0], a01 = A[j*4+1], a10 = A[j*4+2], a11 = A[j*4+3];
    const float g00 = 0.5f*(a00*a00 + a01*a01);
    const float g01 = 0.5f*(a00*a10 + a01*a11);
    const float g11 = 0.5f*(a10*a10 + a11*a11);
    const float det = g00*g11 - g01*g01;

    const float m0 = mu[j*2+0], m1 = mu[j*2+1];
    const float Gmu0 = g00*m0 + g01*m1;
    const float Gmu1 = g01*m0 + g11*m1;
    const float cst  = m0*Gmu0 + m1*Gmu1;

    const float wj = w[j];
    float mx = wj;
    #pragma unroll
    for (int m = 1; m < 64; m <<= 1)
        mx = fmaxf(mx, __shfl_xor(mx, m, 64));
    float se = exp2n((wj - mx) * L2E);
    #pragma unroll
    for (int m = 1; m < 64; m <<= 1)
        se += __shfl_xor(se, m, 64);
    const float lse  = mx + log2n(se) * LN2;
    const float wlog = wj - lse + 0.5f * log2n(det) * LN2;

    cf[0*M_COMP+j] = -g00 * L2E;
    cf[1*M_COMP+j] = -(g01+g01) * L2E;
    cf[2*M_COMP+j] = -g11 * L2E;
    cf[3*M_COMP+j] = (Gmu0+Gmu0) * L2E;
    cf[4*M_COMP+j] = (Gmu1+Gmu1) * L2E;
    cf[5*M_COMP+j] = (wlog - cst) * L2E;
}

// ---------------------------------------------------------------------------
// Kernel 2 — component-split for occupancy. Block = 256 threads = 4 waves;
// all 4 waves process the SAME 256 points (lane L owns points base+4L..+3,
// two float4 loads, waves 1-3 hit L1), wave q handles component quarter
// [16q, 16q+16). 3907 blocks -> occupancy capped at 8 waves/SIMD (2.1x the
// previous 3.8). Max-free logsumexp makes the merge a plain sum of the 4
// per-quarter partials: ds_write_b128 + barrier + 4 conflict-free ds_read_b32.
// Inner math identical to the 17.8us kernel: 2 packed v2f pipelines,
// native v_exp_f32, coefs as float4 loads (L1-hot, 1.5 KB).
// unroll 1 on the chunk loop keeps the coef window at 24 VGPRs (occupancy
// is the whole bet; R5 lesson: pressure explosions are catastrophic).
// ---------------------------------------------------------------------------
__global__ __launch_bounds__(256) void gm_ll(
    const float* __restrict__ sample, // (N,2)
    const float* __restrict__ cf,     // (6,64) in d_ws
    float* __restrict__ out)          // (N,1)
{
    __shared__ float part[4][256];    // [quarter][point-in-block] partial sums

    const float LN2 = 0.6931471805599453f;
    const int tid  = threadIdx.x;
    const int L    = tid & 63;        // point-group lane
    const int q    = tid >> 6;        // component quarter = wave index
    const int base = blockIdx.x * 256;

    const int  p0 = base + 4*L;       // 4 consecutive points
    const bool ok = p0 < N_PTS;       // N%4==0
    const int  pl = ok ? p0 : 0;      // clamp OOB, keep wave intact

    const float4* s4 = (const float4*)sample;
    const float4 qa = s4[(pl >> 1) + 0];     // points p0, p0+1
    const float4 qb = s4[(pl >> 1) + 1];     // points p0+2, p0+3

    const v2f ax0 = {qa.x, qa.z}, ax1 = {qa.y, qa.w};
    const v2f bx0 = {qb.x, qb.z}, bx1 = {qb.y, qb.w};
    const v2f axx0 = ax0*ax0, ax01 = ax0*ax1, axx1 = ax1*ax1;
    const v2f bxx0 = bx0*bx0, bx01 = bx0*bx1, bxx1 = bx1*bx1;

    v2f accA = {0.f, 0.f};            // points p0, p0+1
    v2f accB = {0.f, 0.f};            // points p0+2, p0+3

    const float* cfq = cf + q * 16;   // this wave's quarter

    #pragma unroll 1
    for (int jc = 0; jc < 16; jc += 4) {
        const float4 c0 = *(const float4*)&cfq[0*M_COMP+jc];
        const float4 c1 = *(const float4*)&cfq[1*M_COMP+jc];
        const float4 c2 = *(const float4*)&cfq[2*M_COMP+jc];
        const float4 c3 = *(const float4*)&cfq[3*M_COMP+jc];
        const float4 c4 = *(const float4*)&cfq[4*M_COMP+jc];
        const float4 c5 = *(const float4*)&cfq[5*M_COMP+jc];

#define GM_COMP(F)                                                      \
        {                                                               \
            v2f s = {c5.F, c5.F};                                       \
            s = __builtin_elementwise_fma(ax1,  (v2f){c4.F, c4.F}, s);  \
            s = __builtin_elementwise_fma(ax0,  (v2f){c3.F, c3.F}, s);  \
            s = __builtin_elementwise_fma(axx1, (v2f){c2.F, c2.F}, s);  \
            s = __builtin_elementwise_fma(ax01, (v2f){c1.F, c1.F}, s);  \
            s = __builtin_elementwise_fma(axx0, (v2f){c0.F, c0.F}, s);  \
            accA[0] += exp2n(s[0]);                                     \
            accA[1] += exp2n(s[1]);                                     \
            v2f r = {c5.F, c5.F};                                       \
            r = __builtin_elementwise_fma(bx1,  (v2f){c4.F, c4.F}, r);  \
            r = __builtin_elementwise_fma(bx0,  (v2f){c3.F, c3.F}, r);  \
            r = __builtin_elementwise_fma(bxx1, (v2f){c2.F, c2.F}, r);  \
            r = __builtin_elementwise_fma(bx01, (v2f){c1.F, c1.F}, r);  \
            r = __builtin_elementwise_fma(bxx0, (v2f){c0.F, c0.F}, r);  \
            accB[0] += exp2n(r[0]);                                     \
            accB[1] += exp2n(r[1]);                                     \
        }
        GM_COMP(x)
        GM_COMP(y)
        GM_COMP(z)
        GM_COMP(w)
#undef GM_COMP
    }

    // partial sums for points 4L..4L+3 of this quarter -> LDS
    float4 pw;
    pw.x = accA[0]; pw.y = accA[1]; pw.z = accB[0]; pw.w = accB[1];
    *(float4*)&part[q][4*L] = pw;     // 16B aligned, one ds_write_b128
    __syncthreads();

    // each thread merges one point: consecutive tid -> consecutive LDS
    // addresses per quarter plane -> conflict-free ds_read_b32
    const int pg = base + tid;
    if (pg < N_PTS) {
        const float sum = part[0][tid] + part[1][tid]
                        + part[2][tid] + part[3][tid];
        out[pg] = log2n(sum) * LN2;
    }
}

extern "C" void kernel_launch(void* const* d_in, const int* in_sizes, int n_in,
                              void* d_out, int out_size, void* d_ws, size_t ws_size,
                              hipStream_t stream)
{
    const float* sample = (const float*)d_in[0];  // (1e6, 2) f32
    const float* mu     = (const float*)d_in[1];  // (64, 2)  f32
    const float* A      = (const float*)d_in[2];  // (64,2,2) f32
    const float* w      = (const float*)d_in[3];  // (64, 1)  f32
    float* out = (float*)d_out;                   // (1e6, 1) f32
    float* cf  = (float*)d_ws;                    // 6*64 floats = 1.5 KB

    gm_coef<<<1, 64, 0, stream>>>(mu, A, w, cf);

    const int blocks = (N_PTS + 255) / 256;       // 3907, 256 points/block
    gm_ll<<<blocks, 256, 0, stream>>>(sample, cf, out);
}